// Round 8
// baseline (487.778 us; speedup 1.0000x reference)
//
#include <hip/hip_runtime.h>
#include <math.h>

// CapsuleLayer dynamic routing, fp32 in/out. B=256, I=2048, K=8, J=10, D=16.
// R8 = R7 persistent frame + (1) distributed reduce+squash across ALL 512 blocks
// (5 (b,j) pairs per block, no idle blocks at barriers) + (2) 2-i ILP in the
// USE_C round loop (two independent MFMA->dot->softmax chains interleaved).
// Frame: prep_kernel (zero cnt, cast W->bf16, transpose x->xTb) then caps_kernel
// (512 blocks = exactly 2/CU co-resident, 5 software grid barriers, G16 pattern).
// mfma_f32_16x16x32_bf16: C/D col=lane&15=b, row=(lane>>4)*4+reg=d.
// Round 1 packs 4 i into K=32 (kc=q*8+k -> i_local=q); rounds 2/3 use kc 0..7.
// Routing logits are linear in accumulated v (round 3 uses v1+v2).
// Fallback to multi-kernel path if occupancy query says < 2 blocks/CU.
//
// ws: cnt i32[64] | vT f32[40960] | p f32[16*128*2560] | xTb bf16 | Wb bf16 (~34.8 MB)

#define BB 256
#define II 2048
#define KK 8
#define JJ 10
#define DD 16
#define NCH 128    // i-chunks of 16
#define NBLK 512   // persistent grid: 2 blocks/CU on 256 CUs

typedef __attribute__((ext_vector_type(4))) float f32x4;
typedef __attribute__((ext_vector_type(8))) short short8;

__device__ __forceinline__ short f2bf(float f) {
    union { float f; unsigned u; } v; v.f = f;
    unsigned r = v.u + 0x7FFFu + ((v.u >> 16) & 1u);   // RNE
    return (short)(r >> 16);
}

// ---------------- prep: zero counters + cast W + transpose x ----------------
__global__ __launch_bounds__(256) void prep_kernel(const float* __restrict__ x,
                                                   const float* __restrict__ W,
                                                   short* __restrict__ xTb,
                                                   short* __restrict__ Wb,
                                                   int* __restrict__ cnt) {
    __shared__ float4 tile[8 * 66];
    const int t = threadIdx.x;
    if (blockIdx.x == 0 && t < 16) cnt[t] = 0;

    for (int r = blockIdx.x * 256 + t; r < JJ * II * DD; r += NBLK * 256) {
        const float4* src = (const float4*)(W + (size_t)r * 8);
        const float4 a = src[0], b = src[1];
        short8 o;
        o[0] = f2bf(a.x); o[1] = f2bf(a.y); o[2] = f2bf(a.z); o[3] = f2bf(a.w);
        o[4] = f2bf(b.x); o[5] = f2bf(b.y); o[6] = f2bf(b.z); o[7] = f2bf(b.w);
        *(short8*)(Wb + (size_t)r * 8) = o;
    }

    for (int tl = blockIdx.x; tl < 2048; tl += NBLK) {
        const int i0 = (tl & 255) * 8, b0 = (tl >> 8) * 32;
        __syncthreads();
        {
            const int lb = t >> 3, li = t & 7;
            const float4* src = (const float4*)(x + ((b0 + lb) * II + (i0 + li)) * KK);
            tile[li * 66 + lb * 2 + 0] = src[0];
            tile[li * 66 + lb * 2 + 1] = src[1];
        }
        __syncthreads();
        {
            const int ri = t >> 5, rb = t & 31;
            const float4 p0 = tile[ri * 66 + rb * 2 + 0];
            const float4 p1 = tile[ri * 66 + rb * 2 + 1];
            short8 o;
            o[0] = f2bf(p0.x); o[1] = f2bf(p0.y); o[2] = f2bf(p0.z); o[3] = f2bf(p0.w);
            o[4] = f2bf(p1.x); o[5] = f2bf(p1.y); o[6] = f2bf(p1.z); o[7] = f2bf(p1.w);
            *(short8*)(xTb + ((size_t)(i0 + ri) * BB + (b0 + rb)) * KK) = o;
        }
    }
}

// ---------------- software grid barrier (device-scope, monotonic) ----------------
__device__ __forceinline__ void gbar(int* cnt, int phase) {
    __syncthreads();
    if (threadIdx.x == 0) {
        __threadfence();
        __hip_atomic_fetch_add(&cnt[phase], 1, __ATOMIC_RELEASE, __HIP_MEMORY_SCOPE_AGENT);
        while (__hip_atomic_load(&cnt[phase], __ATOMIC_ACQUIRE, __HIP_MEMORY_SCOPE_AGENT) < NBLK)
            __builtin_amdgcn_s_sleep(1);
    }
    __syncthreads();
}

// ---------------- round body ----------------
// LDS per buffer: W at j*1024+il*128+d*8 (shorts), x at 10240+il*512+b*8. 14336 shorts.
__device__ __forceinline__ void seg_src_dst(int s, int i0, int b0,
                                            const short* __restrict__ xTb,
                                            const short* __restrict__ Wb,
                                            const short** src, int* dst) {
    if (s < 20) {
        const int j = s >> 1, h = s & 1;
        *src = Wb + ((size_t)(j * II + i0) * DD) * KK + h * 512;
        *dst = j * 1024 + h * 512;
    } else {
        const int il = s - 20;
        *src = xTb + ((size_t)(i0 + il) * BB + b0) * KK;
        *dst = 10240 + il * 512;
    }
}

template <int USE_C>
__device__ __forceinline__ void round_body(short (*L)[14336],
    const short* __restrict__ xTb, const short* __restrict__ Wb,
    const float* __restrict__ vT, float* __restrict__ p, int chunk, int bgroup)
{
    const int t = threadIdx.x;
    const int lane = t & 63, wv = t >> 6;
    const int col = lane & 15, q = lane >> 4;
    const int b0 = bgroup * 64;
    const int bl = wv * 16 + col;
    const int i0 = chunk * 16;

    short8 r0[7], r1[7];
#pragma unroll
    for (int n = 0; n < 7; ++n) {
        const int s = wv + n * 4;
        const short* src; int dst;
        seg_src_dst(s, i0, b0, xTb, Wb, &src, &dst);
        r0[n] = *(const short8*)(src + lane * 8);
        seg_src_dst(s, i0 + 8, b0, xTb, Wb, &src, &dst);
        r1[n] = *(const short8*)(src + lane * 8);
    }
#pragma unroll
    for (int n = 0; n < 7; ++n) {
        const int s = wv + n * 4;
        const short* src; int dst;
        seg_src_dst(s, i0, b0, xTb, Wb, &src, &dst);
        *(short8*)(&L[0][dst + lane * 8]) = r0[n];
    }
    __syncthreads();

    f32x4 sfrag[JJ];
#pragma unroll
    for (int j = 0; j < JJ; ++j) sfrag[j] = (f32x4){0.f, 0.f, 0.f, 0.f};

    float vfrag[JJ][4];
    if (USE_C) {
#pragma unroll
        for (int j = 0; j < JJ; ++j)
#pragma unroll
            for (int r = 0; r < 4; ++r)
                vfrag[j][r] = vT[(j * DD + q * 4 + r) * BB + b0 + bl];
    }

#pragma unroll
    for (int sc = 0; sc < 2; ++sc) {
        const short* Lb = L[sc];
        if (USE_C) {
            // 2-i ILP: two independent MFMA->dot->softmax chains per iteration
            for (int il = 0; il < 8; il += 2) {
                const short8 z = (short8){0, 0, 0, 0, 0, 0, 0, 0};
                short8 Bf0 = z, Bf1 = z;
                if (q == 0) {
                    Bf0 = *(const short8*)(&Lb[10240 + il * 512 + bl * 8]);
                    Bf1 = *(const short8*)(&Lb[10240 + (il + 1) * 512 + bl * 8]);
                }
                f32x4 U0[JJ], U1[JJ];
                float Lg0[JJ], Lg1[JJ];
#pragma unroll
                for (int j = 0; j < JJ; ++j) {
                    short8 A0 = z, A1 = z;
                    if (q == 0) {
                        A0 = *(const short8*)(&Lb[j * 1024 + il * 128 + col * 8]);
                        A1 = *(const short8*)(&Lb[j * 1024 + (il + 1) * 128 + col * 8]);
                    }
                    U0[j] = __builtin_amdgcn_mfma_f32_16x16x32_bf16(
                        A0, Bf0, (f32x4){0.f, 0.f, 0.f, 0.f}, 0, 0, 0);
                    U1[j] = __builtin_amdgcn_mfma_f32_16x16x32_bf16(
                        A1, Bf1, (f32x4){0.f, 0.f, 0.f, 0.f}, 0, 0, 0);
                    Lg0[j] = vfrag[j][0] * U0[j][0] + vfrag[j][1] * U0[j][1]
                           + vfrag[j][2] * U0[j][2] + vfrag[j][3] * U0[j][3];
                    Lg1[j] = vfrag[j][0] * U1[j][0] + vfrag[j][1] * U1[j][1]
                           + vfrag[j][2] * U1[j][2] + vfrag[j][3] * U1[j][3];
                }
#pragma unroll
                for (int j = 0; j < JJ; ++j) {   // reduce over the 4 d-quads
                    Lg0[j] += __shfl_xor(Lg0[j], 16, 64);
                    Lg1[j] += __shfl_xor(Lg1[j], 16, 64);
                    Lg0[j] += __shfl_xor(Lg0[j], 32, 64);
                    Lg1[j] += __shfl_xor(Lg1[j], 32, 64);
                }
                float sum0 = 0.f, sum1 = 0.f;   // |logit| O(1): no max-subtract
#pragma unroll
                for (int j = 0; j < JJ; ++j) {
                    Lg0[j] = __expf(Lg0[j]); sum0 += Lg0[j];
                    Lg1[j] = __expf(Lg1[j]); sum1 += Lg1[j];
                }
                const float inv0 = __builtin_amdgcn_rcpf(sum0);
                const float inv1 = __builtin_amdgcn_rcpf(sum1);
#pragma unroll
                for (int j = 0; j < JJ; ++j) {
                    const float c0 = Lg0[j] * inv0, c1 = Lg1[j] * inv1;
#pragma unroll
                    for (int r = 0; r < 4; ++r)
                        sfrag[j][r] += c0 * U0[j][r] + c1 * U1[j][r];
                }
            }
        } else {
            // round 1: sum_i U; pack 4 i per MFMA: kc = q*8+k -> i_local = q
#pragma unroll
            for (int g = 0; g < 2; ++g) {
                const int il = g * 4 + q;
                const short8 Bf = *(const short8*)(&Lb[10240 + il * 512 + bl * 8]);
#pragma unroll
                for (int j = 0; j < JJ; ++j) {
                    const short8 Aj = *(const short8*)(&Lb[j * 1024 + il * 128 + col * 8]);
                    sfrag[j] = __builtin_amdgcn_mfma_f32_16x16x32_bf16(Aj, Bf, sfrag[j], 0, 0, 0);
                }
            }
        }
        if (sc == 0) {
#pragma unroll
            for (int n = 0; n < 7; ++n) {
                const int s = wv + n * 4;
                const short* src; int dst;
                seg_src_dst(s, i0 + 8, b0, xTb, Wb, &src, &dst);
                *(short8*)(&L[1][dst + lane * 8]) = r1[n];
            }
            __syncthreads();
        }
    }

    float* pp = p + ((size_t)(bgroup * 4 + wv) * NCH + chunk) * (JJ * 256);
#pragma unroll
    for (int j = 0; j < JJ; ++j)
        *(f32x4*)(pp + (j * 64 + lane) * 4) = sfrag[j];
}

// ---------------- distributed reduce+squash: 5 (b,j) pairs per block ----------------
// p element (bt,ch,j,d,bc) at bt*NCH*2560 + ch*2560 + j*256 + (d>>2)*64 + bc*4 + (d&3)
__device__ __forceinline__ void rs_all(float* lds,
    const float* __restrict__ p, float* __restrict__ vT, float* __restrict__ out,
    float scale, int mode, int bid)
{
    const int t = threadIdx.x;
    const int d = t & 15, g = t >> 4;   // 16 d x 16 chunk-groups
#pragma unroll
    for (int m = 0; m < 5; ++m) {
        const int pid = bid * 5 + m;            // 0..2559
        const int b = pid / JJ, j = pid % JJ;
        const int bt = b >> 4, bc = b & 15;
        const float* pp = p + (size_t)bt * NCH * 2560 + j * 256
                        + (d >> 2) * 64 + bc * 4 + (d & 3);
        float s = 0.f;
#pragma unroll
        for (int sit = 0; sit < 8; ++sit) s += pp[(size_t)(g + sit * 16) * 2560];
        lds[m * 256 + t] = s;
    }
    __syncthreads();
    if (t < 16) {   // lane t = d; finalize the 5 pairs in wave 0
#pragma unroll
        for (int m = 0; m < 5; ++m) {
            const int pid = bid * 5 + m;
            const int b = pid / JJ, j = pid % JJ;
            float s = 0.f;
#pragma unroll
            for (int g2 = 0; g2 < 16; ++g2) s += lds[m * 256 + g2 * 16 + t];
            s *= scale;
            float ss = s * s;   // norm over the 16 d's (lanes 0..15)
            ss += __shfl_xor(ss, 1, 64);
            ss += __shfl_xor(ss, 2, 64);
            ss += __shfl_xor(ss, 4, 64);
            ss += __shfl_xor(ss, 8, 64);
            const float coef = ss / (1.f + ss) / sqrtf(ss + 1e-7f);
            const float v = coef * s;
            if (mode == 0)      vT[(j * DD + t) * BB + b] = v;
            else if (mode == 1) vT[(j * DD + t) * BB + b] += v;
            else                out[(b * JJ + j) * DD + t] = v;
        }
    }
}

// ---------------- persistent fused kernel ----------------
__global__ __launch_bounds__(256, 2) void caps_kernel(
    const short* __restrict__ xTb, const short* __restrict__ Wb,
    float* __restrict__ vT, float* __restrict__ p, float* __restrict__ out,
    int* __restrict__ cnt)
{
    __shared__ short Ls[2][14336];
    float* lds = (float*)&Ls[0][0];
    const int bid = blockIdx.x;
    const int chunk = bid & (NCH - 1), bgroup = bid >> 7;

    round_body<0>(Ls, xTb, Wb, vT, p, chunk, bgroup);
    gbar(cnt, 0);
    rs_all(lds, p, vT, out, 0.1f, 0, bid);
    gbar(cnt, 1);
    round_body<1>(Ls, xTb, Wb, vT, p, chunk, bgroup);
    gbar(cnt, 2);
    rs_all(lds, p, vT, out, 1.0f, 1, bid);
    gbar(cnt, 3);
    round_body<1>(Ls, xTb, Wb, vT, p, chunk, bgroup);
    gbar(cnt, 4);
    rs_all(lds, p, vT, out, 1.0f, 2, bid);
}

// ---------------- multi-kernel fallback ----------------
template <int USE_C>
__global__ __launch_bounds__(256) void round_mfma_k(const short* __restrict__ xTb,
                                                    const short* __restrict__ Wb,
                                                    const float* __restrict__ vT,
                                                    float* __restrict__ p) {
    __shared__ short Ls[2][14336];
    round_body<USE_C>(Ls, xTb, Wb, vT, p, blockIdx.x, blockIdx.y);
}

__global__ __launch_bounds__(256) void rs_k(const float* __restrict__ p,
                                            float* __restrict__ vT,
                                            float* __restrict__ out,
                                            float scale, int mode) {
    __shared__ float lds[5 * 256];
    rs_all(lds, p, vT, out, scale, mode, blockIdx.x);
}

extern "C" void kernel_launch(void* const* d_in, const int* in_sizes, int n_in,
                              void* d_out, int out_size, void* d_ws, size_t ws_size,
                              hipStream_t stream) {
    const float* x = (const float*)d_in[0];   // [B, I, K]
    const float* W = (const float*)d_in[1];   // [J, I, D, K]
    float* out = (float*)d_out;               // [B, J, D]

    int*   cnt = (int*)d_ws;                            // 64 i32
    float* vT  = (float*)d_ws + 64;                     // 40960 f32
    float* p   = vT + BB * JJ * DD;                     // 16*NCH*2560 f32
    short* xTb = (short*)(p + (size_t)16 * NCH * 2560); // I*B*K bf16
    short* Wb  = xTb + (size_t)II * BB * KK;            // J*I*D*K bf16

    int occ = 0;
    hipError_t oe = hipOccupancyMaxActiveBlocksPerMultiprocessor(&occ, caps_kernel, 256, 0);

    prep_kernel<<<NBLK, 256, 0, stream>>>(x, W, xTb, Wb, cnt);

    if (oe == hipSuccess && occ >= 2) {
        caps_kernel<<<NBLK, 256, 0, stream>>>(xTb, Wb, vT, p, out, cnt);
    } else {
        dim3 rg(NCH, 4);
        round_mfma_k<0><<<rg, 256, 0, stream>>>(xTb, Wb, vT, p);
        rs_k<<<NBLK, 256, 0, stream>>>(p, vT, out, 0.1f, 0);
        round_mfma_k<1><<<rg, 256, 0, stream>>>(xTb, Wb, vT, p);
        rs_k<<<NBLK, 256, 0, stream>>>(p, vT, out, 1.0f, 1);
        round_mfma_k<1><<<rg, 256, 0, stream>>>(xTb, Wb, vT, p);
        rs_k<<<NBLK, 256, 0, stream>>>(p, vT, out, 1.0f, 2);
    }
}

// Round 9
// 467.551 us; speedup vs baseline: 1.0433x; 1.0433x over previous
//
#include <hip/hip_runtime.h>
#include <math.h>

// CapsuleLayer dynamic routing, fp32 in/out. B=256, I=2048, K=8, J=10, D=16.
// R9 = R7 persistent frame + 2-i ILP round body (R8) with the register budget
// PINNED via amdgpu_waves_per_eu(2,2) (R8 spilled at the compiler's 128-VGPR
// heuristic: FETCH 767MB/WRITE 1.1GB scratch traffic), and rs reverted to R7's
// coalesced 160-block form (R8's distributed rs over-fetched 4x: 16B clusters
// spread over 1KB rows).
// Frame: prep_kernel (zero cnt, cast W->bf16, transpose x->xTb) then caps_kernel
// (512 blocks = exactly 2/CU co-resident, 5 software grid barriers, G16 pattern).
// mfma_f32_16x16x32_bf16: C/D col=lane&15=b, row=(lane>>4)*4+reg=d.
// Round 1 packs 4 i into K=32 (kc=q*8+k -> i_local=q); rounds 2/3 use kc 0..7.
// Routing logits are linear in accumulated v (round 3 uses v1+v2).
// Fallback to multi-kernel path if occupancy query says < 2 blocks/CU.
//
// ws: cnt i32[64] | vT f32[40960] | p f32[16*128*2560] | xTb bf16 | Wb bf16 (~34.8 MB)

#define BB 256
#define II 2048
#define KK 8
#define JJ 10
#define DD 16
#define NCH 128    // i-chunks of 16
#define NBLK 512   // persistent grid: 2 blocks/CU on 256 CUs

typedef __attribute__((ext_vector_type(4))) float f32x4;
typedef __attribute__((ext_vector_type(8))) short short8;

__device__ __forceinline__ short f2bf(float f) {
    union { float f; unsigned u; } v; v.f = f;
    unsigned r = v.u + 0x7FFFu + ((v.u >> 16) & 1u);   // RNE
    return (short)(r >> 16);
}

// ---------------- prep: zero counters + cast W + transpose x ----------------
__global__ __launch_bounds__(256) void prep_kernel(const float* __restrict__ x,
                                                   const float* __restrict__ W,
                                                   short* __restrict__ xTb,
                                                   short* __restrict__ Wb,
                                                   int* __restrict__ cnt) {
    __shared__ float4 tile[8 * 66];
    const int t = threadIdx.x;
    if (blockIdx.x == 0 && t < 16) cnt[t] = 0;

    for (int r = blockIdx.x * 256 + t; r < JJ * II * DD; r += NBLK * 256) {
        const float4* src = (const float4*)(W + (size_t)r * 8);
        const float4 a = src[0], b = src[1];
        short8 o;
        o[0] = f2bf(a.x); o[1] = f2bf(a.y); o[2] = f2bf(a.z); o[3] = f2bf(a.w);
        o[4] = f2bf(b.x); o[5] = f2bf(b.y); o[6] = f2bf(b.z); o[7] = f2bf(b.w);
        *(short8*)(Wb + (size_t)r * 8) = o;
    }

    for (int tl = blockIdx.x; tl < 2048; tl += NBLK) {
        const int i0 = (tl & 255) * 8, b0 = (tl >> 8) * 32;
        __syncthreads();
        {
            const int lb = t >> 3, li = t & 7;
            const float4* src = (const float4*)(x + ((b0 + lb) * II + (i0 + li)) * KK);
            tile[li * 66 + lb * 2 + 0] = src[0];
            tile[li * 66 + lb * 2 + 1] = src[1];
        }
        __syncthreads();
        {
            const int ri = t >> 5, rb = t & 31;
            const float4 p0 = tile[ri * 66 + rb * 2 + 0];
            const float4 p1 = tile[ri * 66 + rb * 2 + 1];
            short8 o;
            o[0] = f2bf(p0.x); o[1] = f2bf(p0.y); o[2] = f2bf(p0.z); o[3] = f2bf(p0.w);
            o[4] = f2bf(p1.x); o[5] = f2bf(p1.y); o[6] = f2bf(p1.z); o[7] = f2bf(p1.w);
            *(short8*)(xTb + ((size_t)(i0 + ri) * BB + (b0 + rb)) * KK) = o;
        }
    }
}

// ---------------- software grid barrier (device-scope, monotonic) ----------------
__device__ __forceinline__ void gbar(int* cnt, int phase) {
    __syncthreads();
    if (threadIdx.x == 0) {
        __threadfence();
        __hip_atomic_fetch_add(&cnt[phase], 1, __ATOMIC_RELEASE, __HIP_MEMORY_SCOPE_AGENT);
        while (__hip_atomic_load(&cnt[phase], __ATOMIC_ACQUIRE, __HIP_MEMORY_SCOPE_AGENT) < NBLK)
            __builtin_amdgcn_s_sleep(1);
    }
    __syncthreads();
}

// ---------------- round body (2-i ILP, validated R8) ----------------
// LDS per buffer: W at j*1024+il*128+d*8 (shorts), x at 10240+il*512+b*8. 14336 shorts.
__device__ __forceinline__ void seg_src_dst(int s, int i0, int b0,
                                            const short* __restrict__ xTb,
                                            const short* __restrict__ Wb,
                                            const short** src, int* dst) {
    if (s < 20) {
        const int j = s >> 1, h = s & 1;
        *src = Wb + ((size_t)(j * II + i0) * DD) * KK + h * 512;
        *dst = j * 1024 + h * 512;
    } else {
        const int il = s - 20;
        *src = xTb + ((size_t)(i0 + il) * BB + b0) * KK;
        *dst = 10240 + il * 512;
    }
}

template <int USE_C>
__device__ __forceinline__ void round_body(short (*L)[14336],
    const short* __restrict__ xTb, const short* __restrict__ Wb,
    const float* __restrict__ vT, float* __restrict__ p, int chunk, int bgroup)
{
    const int t = threadIdx.x;
    const int lane = t & 63, wv = t >> 6;
    const int col = lane & 15, q = lane >> 4;
    const int b0 = bgroup * 64;
    const int bl = wv * 16 + col;
    const int i0 = chunk * 16;

    short8 r0[7], r1[7];
#pragma unroll
    for (int n = 0; n < 7; ++n) {
        const int s = wv + n * 4;
        const short* src; int dst;
        seg_src_dst(s, i0, b0, xTb, Wb, &src, &dst);
        r0[n] = *(const short8*)(src + lane * 8);
        seg_src_dst(s, i0 + 8, b0, xTb, Wb, &src, &dst);
        r1[n] = *(const short8*)(src + lane * 8);
    }
#pragma unroll
    for (int n = 0; n < 7; ++n) {
        const int s = wv + n * 4;
        const short* src; int dst;
        seg_src_dst(s, i0, b0, xTb, Wb, &src, &dst);
        *(short8*)(&L[0][dst + lane * 8]) = r0[n];
    }
    __syncthreads();

    f32x4 sfrag[JJ];
#pragma unroll
    for (int j = 0; j < JJ; ++j) sfrag[j] = (f32x4){0.f, 0.f, 0.f, 0.f};

    float vfrag[JJ][4];
    if (USE_C) {
#pragma unroll
        for (int j = 0; j < JJ; ++j)
#pragma unroll
            for (int r = 0; r < 4; ++r)
                vfrag[j][r] = vT[(j * DD + q * 4 + r) * BB + b0 + bl];
    }

#pragma unroll
    for (int sc = 0; sc < 2; ++sc) {
        const short* Lb = L[sc];
        if (USE_C) {
            // 2-i ILP: two independent MFMA->dot->softmax chains per iteration
            for (int il = 0; il < 8; il += 2) {
                const short8 z = (short8){0, 0, 0, 0, 0, 0, 0, 0};
                short8 Bf0 = z, Bf1 = z;
                if (q == 0) {
                    Bf0 = *(const short8*)(&Lb[10240 + il * 512 + bl * 8]);
                    Bf1 = *(const short8*)(&Lb[10240 + (il + 1) * 512 + bl * 8]);
                }
                f32x4 U0[JJ], U1[JJ];
                float Lg0[JJ], Lg1[JJ];
#pragma unroll
                for (int j = 0; j < JJ; ++j) {
                    short8 A0 = z, A1 = z;
                    if (q == 0) {
                        A0 = *(const short8*)(&Lb[j * 1024 + il * 128 + col * 8]);
                        A1 = *(const short8*)(&Lb[j * 1024 + (il + 1) * 128 + col * 8]);
                    }
                    U0[j] = __builtin_amdgcn_mfma_f32_16x16x32_bf16(
                        A0, Bf0, (f32x4){0.f, 0.f, 0.f, 0.f}, 0, 0, 0);
                    U1[j] = __builtin_amdgcn_mfma_f32_16x16x32_bf16(
                        A1, Bf1, (f32x4){0.f, 0.f, 0.f, 0.f}, 0, 0, 0);
                    Lg0[j] = vfrag[j][0] * U0[j][0] + vfrag[j][1] * U0[j][1]
                           + vfrag[j][2] * U0[j][2] + vfrag[j][3] * U0[j][3];
                    Lg1[j] = vfrag[j][0] * U1[j][0] + vfrag[j][1] * U1[j][1]
                           + vfrag[j][2] * U1[j][2] + vfrag[j][3] * U1[j][3];
                }
#pragma unroll
                for (int j = 0; j < JJ; ++j) {   // reduce over the 4 d-quads
                    Lg0[j] += __shfl_xor(Lg0[j], 16, 64);
                    Lg1[j] += __shfl_xor(Lg1[j], 16, 64);
                    Lg0[j] += __shfl_xor(Lg0[j], 32, 64);
                    Lg1[j] += __shfl_xor(Lg1[j], 32, 64);
                }
                float sum0 = 0.f, sum1 = 0.f;   // |logit| O(1): no max-subtract
#pragma unroll
                for (int j = 0; j < JJ; ++j) {
                    Lg0[j] = __expf(Lg0[j]); sum0 += Lg0[j];
                    Lg1[j] = __expf(Lg1[j]); sum1 += Lg1[j];
                }
                const float inv0 = __builtin_amdgcn_rcpf(sum0);
                const float inv1 = __builtin_amdgcn_rcpf(sum1);
#pragma unroll
                for (int j = 0; j < JJ; ++j) {
                    const float c0 = Lg0[j] * inv0, c1 = Lg1[j] * inv1;
#pragma unroll
                    for (int r = 0; r < 4; ++r)
                        sfrag[j][r] += c0 * U0[j][r] + c1 * U1[j][r];
                }
            }
        } else {
            // round 1: sum_i U; pack 4 i per MFMA: kc = q*8+k -> i_local = q
#pragma unroll
            for (int g = 0; g < 2; ++g) {
                const int il = g * 4 + q;
                const short8 Bf = *(const short8*)(&Lb[10240 + il * 512 + bl * 8]);
#pragma unroll
                for (int j = 0; j < JJ; ++j) {
                    const short8 Aj = *(const short8*)(&Lb[j * 1024 + il * 128 + col * 8]);
                    sfrag[j] = __builtin_amdgcn_mfma_f32_16x16x32_bf16(Aj, Bf, sfrag[j], 0, 0, 0);
                }
            }
        }
        if (sc == 0) {
#pragma unroll
            for (int n = 0; n < 7; ++n) {
                const int s = wv + n * 4;
                const short* src; int dst;
                seg_src_dst(s, i0 + 8, b0, xTb, Wb, &src, &dst);
                *(short8*)(&L[1][dst + lane * 8]) = r1[n];
            }
            __syncthreads();
        }
    }

    float* pp = p + ((size_t)(bgroup * 4 + wv) * NCH + chunk) * (JJ * 256);
#pragma unroll
    for (int j = 0; j < JJ; ++j)
        *(f32x4*)(pp + (j * 64 + lane) * 4) = sfrag[j];
}

// ---------------- reduce+squash (R7 coalesced form, 160 blocks active) ----------------
// p element (j,d,bc) at j*256 + lane*4 + r, lane=(d>>2)*16+bc, r=d&3.
template <int MODE>
__device__ __forceinline__ void rs_body(float* red, float* cf,
    const float* __restrict__ p, float* __restrict__ vT, float* __restrict__ out,
    float scale, int j, int bt)
{
    const int t = threadIdx.x;
    const int d = t >> 4, bc = t & 15;
    const int lane = (d >> 2) * 16 + bc, r = d & 3;

    const float* pp = p + (size_t)bt * NCH * (JJ * 256) + j * 256 + lane * 4 + r;
    float sum = 0.f;
#pragma unroll 8
    for (int ch = 0; ch < NCH; ++ch) sum += pp[(size_t)ch * (JJ * 256)];
    const float s = sum * scale;

    red[t] = s;
    __syncthreads();
    if (t < 16) {
        float ss = 0.f;
#pragma unroll
        for (int dd = 0; dd < DD; ++dd) {
            const float v = red[dd * 16 + t];
            ss += v * v;
        }
        cf[t] = ss / (1.f + ss) / sqrtf(ss + 1e-7f);
    }
    __syncthreads();
    const float v = cf[bc] * s;
    if (MODE == 0) vT[(j * DD + d) * BB + bt * 16 + bc] = v;
    if (MODE == 1) vT[(j * DD + d) * BB + bt * 16 + bc] += v;
    if (MODE == 2) out[((bt * 16 + bc) * JJ + j) * DD + d] = v;
}

// ---------------- persistent fused kernel ----------------
__global__ __launch_bounds__(256)
__attribute__((amdgpu_waves_per_eu(2, 2)))   // pin 2 waves/EU -> 256-reg budget, no spill
void caps_kernel(
    const short* __restrict__ xTb, const short* __restrict__ Wb,
    float* __restrict__ vT, float* __restrict__ p, float* __restrict__ out,
    int* __restrict__ cnt)
{
    __shared__ short Ls[2][14336];
    float* red = (float*)&Ls[0][0];
    float* cf  = red + 256;
    const int bid = blockIdx.x;
    const int chunk = bid & (NCH - 1), bgroup = bid >> 7;
    const int rj = bid >> 4, rbt = bid & 15;

    round_body<0>(Ls, xTb, Wb, vT, p, chunk, bgroup);
    gbar(cnt, 0);
    if (bid < JJ * 16) rs_body<0>(red, cf, p, vT, out, 0.1f, rj, rbt);
    gbar(cnt, 1);
    round_body<1>(Ls, xTb, Wb, vT, p, chunk, bgroup);
    gbar(cnt, 2);
    if (bid < JJ * 16) rs_body<1>(red, cf, p, vT, out, 1.0f, rj, rbt);
    gbar(cnt, 3);
    round_body<1>(Ls, xTb, Wb, vT, p, chunk, bgroup);
    gbar(cnt, 4);
    if (bid < JJ * 16) rs_body<2>(red, cf, p, vT, out, 1.0f, rj, rbt);
}

// ---------------- multi-kernel fallback ----------------
template <int USE_C>
__global__ __launch_bounds__(256) void round_mfma_k(const short* __restrict__ xTb,
                                                    const short* __restrict__ Wb,
                                                    const float* __restrict__ vT,
                                                    float* __restrict__ p) {
    __shared__ short Ls[2][14336];
    round_body<USE_C>(Ls, xTb, Wb, vT, p, blockIdx.x, blockIdx.y);
}

template <int MODE>
__global__ __launch_bounds__(256) void rs_k(const float* __restrict__ p,
                                            float* __restrict__ vT,
                                            float* __restrict__ out, float scale) {
    __shared__ float red[256 + 16];
    rs_body<MODE>(red, red + 256, p, vT, out, scale, blockIdx.x, blockIdx.y);
}

extern "C" void kernel_launch(void* const* d_in, const int* in_sizes, int n_in,
                              void* d_out, int out_size, void* d_ws, size_t ws_size,
                              hipStream_t stream) {
    const float* x = (const float*)d_in[0];   // [B, I, K]
    const float* W = (const float*)d_in[1];   // [J, I, D, K]
    float* out = (float*)d_out;               // [B, J, D]

    int*   cnt = (int*)d_ws;                            // 64 i32
    float* vT  = (float*)d_ws + 64;                     // 40960 f32
    float* p   = vT + BB * JJ * DD;                     // 16*NCH*2560 f32
    short* xTb = (short*)(p + (size_t)16 * NCH * 2560); // I*B*K bf16
    short* Wb  = xTb + (size_t)II * BB * KK;            // J*I*D*K bf16

    int occ = 0;
    hipError_t oe = hipOccupancyMaxActiveBlocksPerMultiprocessor(&occ, caps_kernel, 256, 0);

    prep_kernel<<<NBLK, 256, 0, stream>>>(x, W, xTb, Wb, cnt);

    if (oe == hipSuccess && occ >= 2) {
        caps_kernel<<<NBLK, 256, 0, stream>>>(xTb, Wb, vT, p, out, cnt);
    } else {
        dim3 rg(NCH, 4);
        dim3 sg(JJ, 16);
        round_mfma_k<0><<<rg, 256, 0, stream>>>(xTb, Wb, vT, p);
        rs_k<0><<<sg, 256, 0, stream>>>(p, vT, out, 0.1f);
        round_mfma_k<1><<<rg, 256, 0, stream>>>(xTb, Wb, vT, p);
        rs_k<1><<<sg, 256, 0, stream>>>(p, vT, out, 1.0f);
        round_mfma_k<1><<<rg, 256, 0, stream>>>(xTb, Wb, vT, p);
        rs_k<2><<<sg, 256, 0, stream>>>(p, vT, out, 1.0f);
    }
}